// Round 6
// baseline (239.465 us; speedup 1.0000x reference)
//
#include <hip/hip_runtime.h>
#include <hip/hip_bf16.h>

// h = x(65536x512) @ W^T(512x256) + bias_lin ; GroupNorm(8 groups of 32)
// ; min over 256 channels -> m[b] ; out[c*B+b] = m[b] + bias[c]
//
// R6 change (theory: output-write scatter paces the kernel). R0-R5 all wrote
// per-iteration: 256 chunks of 128 B at 256 KB stride per block -> chip-wide
// ~65k isolated 2-line DRAM bursts per tile round, draining at 0.8 TB/s;
// duration was invariant to occupancy/shuffles/buffering/barriers, and
// FETCH (66 MB, L3-resident X) shows reads were never the limit.
// New structure: block b owns CONTIGUOUS rows [b*256, b*256+256) (8 tiles;
// X reads = one contiguous 512 KB region), accumulates per-row min into
// m_sh[256] in LDS, and writes output ONCE at the end: per channel a
// contiguous 1 KB run (thread tid>>2 = channel, tid&3 = row quarter).
// Compute structure (W-stationary waves, MFMA D=W·X^T, LDS stats exchange,
// vmcnt-preserving LBARs) unchanged from R5.
#define B_ROWS 65536
#define K_DIM  512
#define N_DIM  256
#define EPS    1e-5f
#define MTILE  32
#define NBLK   256
#define TPB    8                      // tiles per block (contiguous)
#define ROWS_PER_BLK (MTILE * TPB)    // 256
#define STRIDE 520      // 512 + 8 pad (bf16)

using short8  = __attribute__((ext_vector_type(8))) short;
using floatx4 = __attribute__((ext_vector_type(4))) float;

// LDS-only barrier: does NOT drain vmcnt (prefetch loads stay in flight).
#define LBAR() do {                                          \
    __builtin_amdgcn_sched_barrier(0);                       \
    asm volatile("s_waitcnt lgkmcnt(0)" ::: "memory");       \
    __builtin_amdgcn_s_barrier();                            \
    __builtin_amdgcn_sched_barrier(0);                       \
} while (0)

__device__ __forceinline__ unsigned short f2bf(float f) {
    unsigned u = __builtin_bit_cast(unsigned, f);
    u += 0x7FFFu + ((u >> 16) & 1u);     // RNE
    return (unsigned short)(u >> 16);
}

// Pack W (256x512 fp32) into bf16 MFMA fragment order (A/B layouts symmetric
// for 16x16x32):
// P[((nt*16 + kkg)*64 + lane)*8 + j] = bf16(W[nt*16 + (lane&15)][kkg*32 + (lane>>4)*8 + j])
__global__ __launch_bounds__(64) void pack_w(const float* __restrict__ W,
                                             unsigned short* __restrict__ P) {
    int b    = blockIdx.x;           // 0..255
    int nt   = b >> 4, kk = b & 15;
    int lane = threadIdx.x;
    int l15  = lane & 15, quad = lane >> 4;
    const float* src = W + (size_t)(nt * 16 + l15) * K_DIM + kk * 32 + quad * 8;
    short8 v;
#pragma unroll
    for (int j = 0; j < 8; ++j) v[j] = (short)f2bf(src[j]);
    *(short8*)(P + ((size_t)(nt * 16 + kk) * 64 + lane) * 8) = v;
}

__global__ __launch_bounds__(1024) void fused_persistent(
    const float* __restrict__ X, const unsigned short* __restrict__ P,
    const float* __restrict__ bias_lin, const float* __restrict__ wgn,
    const float* __restrict__ bgn, const float* __restrict__ bias,
    float* __restrict__ out)
{
    __shared__ unsigned short Ash[2][MTILE * STRIDE];   // 2 x 33280 B
    __shared__ float smS[16][32];                        // per-wave partial sums
    __shared__ float smSS[16][32];
    __shared__ float smin[16][32];                       // per-wave 16-ch min
    __shared__ float m_sh[ROWS_PER_BLK];                 // per-row min, all 8 tiles

    const int tid  = threadIdx.x;
    const int wave = tid >> 6;            // 0..15; owns channels [16*wave, 16*wave+16)
    const int lane = tid & 63;
    const int l15  = lane & 15, quad = lane >> 4;

    // ---- this wave's W fragments: 16 short8 (nt == wave) ----
    short8 bfr[16];
#pragma unroll
    for (int kkg = 0; kkg < 16; ++kkg)
        bfr[kkg] = *(const short8*)(P + (((size_t)wave * 16 + kkg) * 64 + lane) * 8);

    // per-lane channel params: ch = wave*16 + quad*4 + r
    float blr[4], wgr[4], bgr[4];
#pragma unroll
    for (int r = 0; r < 4; ++r) {
        int c = wave * 16 + quad * 4 + r;
        blr[r] = bias_lin[c]; wgr[r] = wgn[c]; bgr[r] = bgn[c];
    }
    const float bias_c = bias[tid >> 2];   // out channel for the final write phase

    // staging geometry: tile = 32 rows x 128 float4; thread covers rows
    // r0..r0+3 (r0 = (tid>>7)*4) at fp32 cols [c4, c4+4)
    const int r0 = (tid >> 7) * 4;
    const int c4 = (tid & 127) * 4;

    const size_t row_base = (size_t)blockIdx.x * ROWS_PER_BLK;

    // prologue: load + stage tile 0 into buf0, issue prefetch of tile 1
    float4 xq[4];
#pragma unroll
    for (int p = 0; p < 4; ++p)
        xq[p] = *(const float4*)(X + (row_base + r0 + p) * K_DIM + c4);
#pragma unroll
    for (int p = 0; p < 4; ++p) {
        ushort4 h;
        h.x = f2bf(xq[p].x); h.y = f2bf(xq[p].y);
        h.z = f2bf(xq[p].z); h.w = f2bf(xq[p].w);
        *(ushort4*)(&Ash[0][(r0 + p) * STRIDE + c4]) = h;
    }
#pragma unroll
    for (int p = 0; p < 4; ++p)
        xq[p] = *(const float4*)(X + (row_base + MTILE + r0 + p) * K_DIM + c4);
    LBAR();

    int cur = 0;
    for (int it = 0; it < TPB; ++it) {
        // ---- stage NEXT tile into the other buffer (overlaps this K-loop),
        //      then issue prefetch for tile it+2 ----
        if (it + 1 < TPB) {
#pragma unroll
            for (int p = 0; p < 4; ++p) {
                ushort4 h;
                h.x = f2bf(xq[p].x); h.y = f2bf(xq[p].y);
                h.z = f2bf(xq[p].z); h.w = f2bf(xq[p].w);
                *(ushort4*)(&Ash[cur ^ 1][(r0 + p) * STRIDE + c4]) = h;
            }
            if (it + 2 < TPB) {
#pragma unroll
                for (int p = 0; p < 4; ++p)
                    xq[p] = *(const float4*)(X + (row_base + (size_t)(it + 2) * MTILE + r0 + p) * K_DIM + c4);
            }
        }

        // ---- K-loop on current buffer: D[ch16][row32] = W·X^T, bias in C-init ----
        floatx4 acc[2];
#pragma unroll
        for (int rt = 0; rt < 2; ++rt)
#pragma unroll
            for (int r = 0; r < 4; ++r) acc[rt][r] = blr[r];
#pragma unroll
        for (int kk = 0; kk < 16; ++kk) {
            short8 a0 = *(const short8*)&Ash[cur][(l15)      * STRIDE + kk * 32 + quad * 8];
            short8 a1 = *(const short8*)&Ash[cur][(16 + l15) * STRIDE + kk * 32 + quad * 8];
            acc[0] = __builtin_amdgcn_mfma_f32_16x16x32_bf16(bfr[kk], a0, acc[0], 0, 0, 0);
            acc[1] = __builtin_amdgcn_mfma_f32_16x16x32_bf16(bfr[kk], a1, acc[1], 0, 0, 0);
        }

        // ---- GroupNorm stats: in-lane over 4 ch + quad shfl -> wave's 16 ch;
        //      combine with partner wave (wave^1) via LDS ----
        float sreg[2], ssreg[2];
#pragma unroll
        for (int rt = 0; rt < 2; ++rt) {
            float s = 0.f, ss = 0.f;
#pragma unroll
            for (int r = 0; r < 4; ++r) { float v = acc[rt][r]; s += v; ss = fmaf(v, v, ss); }
            s  += __shfl_xor(s, 16);  s  += __shfl_xor(s, 32);
            ss += __shfl_xor(ss, 16); ss += __shfl_xor(ss, 32);
            sreg[rt] = s; ssreg[rt] = ss;
            if (quad == 0) { smS[wave][rt * 16 + l15] = s; smSS[wave][rt * 16 + l15] = ss; }
        }
        LBAR();

#pragma unroll
        for (int rt = 0; rt < 2; ++rt) {
            int row = rt * 16 + l15;
            float st   = sreg[rt]  + smS[wave ^ 1][row];    // 32-ch sums
            float sst  = ssreg[rt] + smSS[wave ^ 1][row];
            float mean = st * (1.0f / 32.0f);
            float var  = sst * (1.0f / 32.0f) - mean * mean;
            float inv  = rsqrtf(var + EPS);
            float mi   = mean * inv;
            float mn   = 1e30f;
#pragma unroll
            for (int r = 0; r < 4; ++r) {
                float g = fmaf(fmaf(acc[rt][r], inv, -mi), wgr[r], bgr[r]);
                mn = fminf(mn, g);
            }
            mn = fminf(mn, __shfl_xor(mn, 16));
            mn = fminf(mn, __shfl_xor(mn, 32));
            if (quad == 0) smin[wave][row] = mn;
        }
        LBAR();

        if (tid < MTILE) {
            float m0 = smin[0][tid];
#pragma unroll
            for (int w = 1; w < 16; ++w) m0 = fminf(m0, smin[w][tid]);
            m_sh[it * MTILE + tid] = m0;
        }
        cur ^= 1;
        // Ash handoff safety: iteration i's staging writes to buf_{i^1} follow
        // this iteration's two barriers, which postdate ALL waves' K-loop
        // reads of that buffer from iteration i-1. m_sh is only read after
        // the final barrier below.
    }

    // ---- deferred bulk write: thread -> channel c = tid>>2, row quarter
    //      q = tid&3; contiguous 64-float run per thread; per channel the
    //      block emits one contiguous 1 KB run ----
    LBAR();
    {
        int c = tid >> 2;
        int q = tid & 3;
        float* dst = out + (size_t)c * B_ROWS + row_base + q * 64;
#pragma unroll
        for (int i = 0; i < 16; ++i) {
            float4 mv = *(const float4*)&m_sh[q * 64 + i * 4];
            float4 o;
            o.x = mv.x + bias_c; o.y = mv.y + bias_c;
            o.z = mv.z + bias_c; o.w = mv.w + bias_c;
            *(float4*)(dst + i * 4) = o;
        }
    }
}

extern "C" void kernel_launch(void* const* d_in, const int* in_sizes, int n_in,
                              void* d_out, int out_size, void* d_ws, size_t ws_size,
                              hipStream_t stream) {
    const float* x    = (const float*)d_in[0];
    const float* w    = (const float*)d_in[1];
    const float* bl   = (const float*)d_in[2];
    const float* wg   = (const float*)d_in[3];
    const float* bg   = (const float*)d_in[4];
    const float* bias = (const float*)d_in[5];

    unsigned short* P = (unsigned short*)d_ws;     // 256 KB packed bf16 W
    float* out = (float*)d_out;

    hipLaunchKernelGGL(pack_w, dim3(256), dim3(64), 0, stream, w, P);
    hipLaunchKernelGGL(fused_persistent, dim3(NBLK), dim3(1024), 0, stream,
                       x, P, bl, wg, bg, bias, out);
}